// Round 11
// baseline (1518.634 us; speedup 1.0000x reference)
//
#include <hip/hip_runtime.h>
#include <hip/hip_cooperative_groups.h>

namespace cg = cooperative_groups;

#define NE_N 50000
#define NP_N 25000
#define E_N 200000
#define DIM 128
#define LOG2E 1.4426950408889634f

typedef __attribute__((ext_vector_type(8))) short short8;
typedef __attribute__((ext_vector_type(4))) float f32x4;

static __device__ __forceinline__ ushort f2bf(float f) {
  unsigned x = __float_as_uint(f);
  return (ushort)((x + 0x7fffu + ((x >> 16) & 1u)) >> 16);  // RNE
}
static __device__ __forceinline__ float bf2f(ushort u) {
  return __uint_as_float(((unsigned)u) << 16);
}

#define SU_CW 12
#define SU_V 6
#define SU_HB 782              // 782*256 >= 200000
#define SU_H (4 * SU_HB)
#define EBLK ((NE_N + 63) / 64)
#define PBLK ((NP_N + 63) / 64)
#define GEMM_BLK (EBLK + PBLK)
#define FILL_BLK (4 * SU_HB)

struct MegaArgs {
  const float *x_elem, *x_proc, *W_src, *W_dst, *att_src, *att_dst, *bias,
      *lin_W, *lin_b;
  const int* esr[4];  // edge src lists
  const int* edl[4];  // edge dst lists
  ushort *xe0, *xe1, *xp0, *xp1;
  unsigned char *hsE0, *hsE1, *hsP3, *hsP2;
  ushort* WbT;
  float *esE0, *esE1, *esP3, *esP2;
  float *edEA, *edEB, *edPA, *edPB;
  float* vec;
  int *parti, *part_excl;
  int* cnt[4];
  float* csum;
  int* rp[4];
  ushort* ss[4];
  ushort* rk[4];
  float* out;
};

// ---------------------------------------------------------------------------
// setup: conv_w | vec | hist+rank (rank = atomicAdd return -> atomic-free fill)
static __device__ void setup_body(int blk, const MegaArgs& a) {
  int tid = threadIdx.x;
  if (blk < SU_CW) {
    const float* src = a.W_src + (size_t)blk * DIM * DIM;
    ushort* dst = a.WbT + (size_t)blk * DIM * DIM;
    for (int i = tid; i < DIM * DIM; i += 256) {
      int k = i >> 7, n = i & 127;
      dst[n * DIM + k] = f2bf(src[i]);
    }
  } else if (blk < SU_CW + SU_V) {
    int b = blk - SU_CW;
    int lt = b * 2 + (tid >> 7);
    int i = tid & 127;
    const float* Wd = a.W_dst + (size_t)lt * DIM * DIM;
    const float* ad = a.att_dst + lt * DIM;
    float s = 0.f;
#pragma unroll 8
    for (int j = 0; j < DIM; j++) s += Wd[i * DIM + j] * ad[j];
    a.vec[lt * DIM + i] = s;
  } else {
    int b = blk - SU_CW - SU_V;
    int ty = b / SU_HB;
    int e = (b % SU_HB) * 256 + tid;
    if (e >= E_N) return;
    a.rk[ty][e] = (ushort)atomicAdd(&a.cnt[ty][a.edl[ty][e]], 1);
  }
}

// ---------------------------------------------------------------------------
// 3-phase hierarchical scan (r9's 1-dispatch variant measured 92us — keep this)
static __device__ void scanA_body(int ty, int bx, const MegaArgs& a) {
  const int* cnt = a.cnt[ty];
  int n = (ty == 0 || ty == 3) ? NE_N : NP_N;
  int nblk = (n + 1023) >> 10;
  if (bx >= nblk) return;
  int base = bx * 1024 + threadIdx.x * 4;
  int s = 0;
#pragma unroll
  for (int j = 0; j < 4; j++) s += (base + j < n) ? cnt[base + j] : 0;
  int lane = threadIdx.x & 63, wv = threadIdx.x >> 6;
#pragma unroll
  for (int off = 32; off > 0; off >>= 1) s += __shfl_xor(s, off, 64);
  __shared__ int ws4[4];
  if (lane == 0) ws4[wv] = s;
  __syncthreads();
  if (threadIdx.x == 0)
    a.parti[ty * 64 + bx] = ws4[0] + ws4[1] + ws4[2] + ws4[3];
}

static __device__ void scanB_body(const MegaArgs& a) {
  int ty = threadIdx.x >> 6, lane = threadIdx.x & 63;
  int n = (ty == 0 || ty == 3) ? NE_N : NP_N;
  int nblk = (n + 1023) >> 10;
  int v = (lane < nblk) ? a.parti[ty * 64 + lane] : 0;
  int sc = v;
#pragma unroll
  for (int off = 1; off < 64; off <<= 1) {
    int t = __shfl_up(sc, off, 64);
    if (lane >= off) sc += t;
  }
  if (lane < nblk) a.part_excl[ty * 64 + lane] = sc - v;
  if (lane == nblk - 1) a.rp[ty][n] = sc;  // total
}

static __device__ void scanC_body(int ty, int bx, const MegaArgs& a) {
  const int* cnt = a.cnt[ty];
  int* rp = a.rp[ty];
  int n = (ty == 0 || ty == 3) ? NE_N : NP_N;
  int nblk = (n + 1023) >> 10;
  if (bx >= nblk) return;
  int base = bx * 1024 + threadIdx.x * 4;
  int v[4];
#pragma unroll
  for (int j = 0; j < 4; j++) v[j] = (base + j < n) ? cnt[base + j] : 0;
  int s = v[0] + v[1] + v[2] + v[3];
  int lane = threadIdx.x & 63, wv = threadIdx.x >> 6;
  int sc = s;
#pragma unroll
  for (int off = 1; off < 64; off <<= 1) {
    int t = __shfl_up(sc, off, 64);
    if (lane >= off) sc += t;
  }
  __shared__ int ws4[4];
  if (lane == 63) ws4[wv] = sc;
  __syncthreads();
  int wbase = 0;
  for (int w = 0; w < wv; w++) wbase += ws4[w];
  int p = a.part_excl[ty * 64 + bx] + wbase + sc - s;
#pragma unroll
  for (int j = 0; j < 4; j++) {
    if (base + j < n) rp[base + j] = p;
    p += v[j];
  }
}

// ---------------------------------------------------------------------------
// atomic-free CSR fill: position = rp[dst] + precomputed rank
static __device__ void fill_one(int b, const MegaArgs& a) {
  int ty = b / SU_HB;
  int e = (b % SU_HB) * 256 + threadIdx.x;
  if (e >= E_N) return;
  a.ss[ty][a.rp[ty][a.edl[ty][e]] + a.rk[ty][e]] = (ushort)a.esr[ty][e];
}

// ---------------------------------------------------------------------------
// GEMM body: operand-swapped MFMA; es (scaled LOG2E) + ed for both dst halves.
// FP32=true: layer 0 reads raw fp32 features.
template <bool FP32>
static __device__ void gemm_body(int blk, const void* __restrict__ xev,
                                 const void* __restrict__ xpv,
                                 const MegaArgs& a, int l) {
  const void* xb;
  const ushort *W0T, *W1T;
  const float *a0, *a1, *dv0, *dv1;
  unsigned char *hs0, *hs1;
  float *es0, *es1, *edA, *edB;
  int N;
  if (blk < EBLK) {
    xb = xev; N = NE_N;
    W0T = a.WbT + (size_t)(l * 4 + 0) * DIM * DIM;
    W1T = a.WbT + (size_t)(l * 4 + 1) * DIM * DIM;
    a0 = a.att_src + (l * 4 + 0) * DIM; a1 = a.att_src + (l * 4 + 1) * DIM;
    dv0 = a.vec + (l * 4 + 0) * DIM; dv1 = a.vec + (l * 4 + 3) * DIM;
    hs0 = a.hsE0; hs1 = a.hsE1; es0 = a.esE0; es1 = a.esE1;
    edA = a.edEA; edB = a.edEB;
  } else {
    blk -= EBLK; xb = xpv; N = NP_N;
    W0T = a.WbT + (size_t)(l * 4 + 3) * DIM * DIM;
    W1T = a.WbT + (size_t)(l * 4 + 2) * DIM * DIM;
    a0 = a.att_src + (l * 4 + 3) * DIM; a1 = a.att_src + (l * 4 + 2) * DIM;
    dv0 = a.vec + (l * 4 + 1) * DIM; dv1 = a.vec + (l * 4 + 2) * DIM;
    hs0 = a.hsP3; hs1 = a.hsP2; es0 = a.esP3; es1 = a.esP2;
    edA = a.edPA; edB = a.edPB;
  }

  const int wave = threadIdx.x >> 6;
  const int lane = threadIdx.x & 63;
  const int m = lane & 15, quad = lane >> 4;
  const int row0 = blk * 64 + wave * 16;
  if (row0 >= N) return;
  int rowA = row0 + m;
  if (rowA >= N) rowA = N - 1;  // clamp loads; stores guarded

  f32x4 acc0[8], acc1[8];
#pragma unroll
  for (int f = 0; f < 8; f++) {
    acc0[f] = (f32x4){0.f, 0.f, 0.f, 0.f};
    acc1[f] = (f32x4){0.f, 0.f, 0.f, 0.f};
  }

  float edp0 = 0.f, edp1 = 0.f;
  const float* xf32 = (const float*)xb + (size_t)rowA * DIM + quad * 8;
  const ushort* xb16 = (const ushort*)xb + (size_t)rowA * DIM + quad * 8;
#pragma unroll
  for (int k0 = 0; k0 < 4; k0++) {
    short8 xv;
    float xf[8];
    if (FP32) {
      float4 f0 = *(const float4*)(xf32 + k0 * 32);
      float4 f1 = *(const float4*)(xf32 + k0 * 32 + 4);
      xf[0] = f0.x; xf[1] = f0.y; xf[2] = f0.z; xf[3] = f0.w;
      xf[4] = f1.x; xf[5] = f1.y; xf[6] = f1.z; xf[7] = f1.w;
#pragma unroll
      for (int j = 0; j < 8; j++) xv[j] = (short)f2bf(xf[j]);
    } else {
      xv = *(const short8*)(xb16 + k0 * 32);
#pragma unroll
      for (int j = 0; j < 8; j++) xf[j] = bf2f((ushort)xv[j]);
    }
    {
      int off = k0 * 32 + quad * 8;
      float4 vA0 = *(const float4*)&dv0[off];
      float4 vA1 = *(const float4*)&dv0[off + 4];
      float4 vB0 = *(const float4*)&dv1[off];
      float4 vB1 = *(const float4*)&dv1[off + 4];
      edp0 += xf[0] * vA0.x + xf[1] * vA0.y + xf[2] * vA0.z + xf[3] * vA0.w +
              xf[4] * vA1.x + xf[5] * vA1.y + xf[6] * vA1.z + xf[7] * vA1.w;
      edp1 += xf[0] * vB0.x + xf[1] * vB0.y + xf[2] * vB0.z + xf[3] * vB0.w +
              xf[4] * vB1.x + xf[5] * vB1.y + xf[6] * vB1.z + xf[7] * vB1.w;
    }
#pragma unroll
    for (int f = 0; f < 8; f++) {
      size_t boff = (size_t)(f * 16 + m) * DIM + k0 * 32 + quad * 8;
      short8 w0 = *(const short8*)(W0T + boff);
      acc0[f] = __builtin_amdgcn_mfma_f32_16x16x32_bf16(w0, xv, acc0[f], 0, 0, 0);
      short8 w1 = *(const short8*)(W1T + boff);
      acc1[f] = __builtin_amdgcn_mfma_f32_16x16x32_bf16(w1, xv, acc1[f], 0, 0, 0);
    }
  }

  const int row = row0 + m;
  edp0 += __shfl_xor(edp0, 16, 64);
  edp0 += __shfl_xor(edp0, 32, 64);
  edp1 += __shfl_xor(edp1, 16, 64);
  edp1 += __shfl_xor(edp1, 32, 64);
  if (quad == 0 && row < N) {
    edA[row] = edp0 * LOG2E;
    edB[row] = edp1 * LOG2E;
  }

#pragma unroll
  for (int set = 0; set < 2; set++) {
    f32x4* acc = set ? acc1 : acc0;
    const float* as = set ? a1 : a0;
    float* es = set ? es1 : es0;
    unsigned char* hs = set ? hs1 : hs0;

    float esum = 0.f;
#pragma unroll
    for (int f = 0; f < 8; f++) {
      float4 av = *(const float4*)&as[f * 16 + quad * 4];
      esum += acc[f][0] * av.x + acc[f][1] * av.y + acc[f][2] * av.z +
              acc[f][3] * av.w;
    }
    esum += __shfl_xor(esum, 16, 64);
    esum += __shfl_xor(esum, 32, 64);
    if (quad == 0 && row < N) es[row] = esum * LOG2E;

    if (row < N) {
#pragma unroll
      for (int f = 0; f < 8; f++) {
        int w = __builtin_amdgcn_cvt_pk_fp8_f32(acc[f][0], acc[f][1], 0, false);
        w = __builtin_amdgcn_cvt_pk_fp8_f32(acc[f][2], acc[f][3], w, true);
        *(unsigned*)&hs[(size_t)row * DIM + f * 16 + quad * 4] = (unsigned)w;
      }
    }
  }
}

// ---------------------------------------------------------------------------
// gather: one 64-lane wave per dst node, 8 edge-slots x 8 sublanes, 16B loads.
static __device__ void gather_one(int wid, const MegaArgs& a, int l,
                                  ushort* __restrict__ outxe,
                                  ushort* __restrict__ outxp) {
  const int lane = threadIdx.x & 63;
  const int slot = lane >> 3, sub = lane & 7;

  int node;
  const int *rpA, *rpB;
  const ushort *ssA, *ssB;
  const float *esA, *esB;
  const unsigned char *hsA, *hsB;
  float edvA, edvB;
  const float *b0, *b1;
  ushort* outb;
  if (wid < NE_N) {  // e-dst: ee (A) + pe (B)
    node = wid;
    rpA = a.rp[0]; ssA = a.ss[0]; esA = a.esE0; hsA = a.hsE0;
    rpB = a.rp[3]; ssB = a.ss[3]; esB = a.esP3; hsB = a.hsP3;
    edvA = a.edEA[node]; edvB = a.edEB[node];
    b0 = a.bias + (l * 4 + 0) * DIM; b1 = a.bias + (l * 4 + 3) * DIM;
    outb = outxe;
  } else {  // p-dst: ep (A) + pp (B)
    node = wid - NE_N;
    rpA = a.rp[1]; ssA = a.ss[1]; esA = a.esE1; hsA = a.hsE1;
    rpB = a.rp[2]; ssB = a.ss[2]; esB = a.esP2; hsB = a.hsP2;
    edvA = a.edPA[node]; edvB = a.edPB[node];
    b0 = a.bias + (l * 4 + 1) * DIM; b1 = a.bias + (l * 4 + 2) * DIM;
    outb = outxp;
  }

  float res[16];
#pragma unroll
  for (int j = 0; j < 16; j++) res[j] = 0.f;

#pragma unroll
  for (int half = 0; half < 2; half++) {
    const int* rp = half ? rpB : rpA;
    const ushort* ss = half ? ssB : ssA;
    const float* es = half ? esB : esA;
    const unsigned char* hs = half ? hsB : hsA;
    const float edv = half ? edvB : edvA;
    const int beg = rp[node], end = rp[node + 1];

    float acc[16];
#pragma unroll
    for (int j = 0; j < 16; j++) acc[j] = 0.f;
    float sw = 0.f;

    for (int e = beg + slot; e < end; e += 8) {
      int s = ss[e];
      float w = exp2f(fmaxf(es[s] + edv, 0.f));
      sw += w;
      uint4 h = *(const uint4*)&hs[(size_t)s * DIM + sub * 16];
      auto p0 = __builtin_amdgcn_cvt_pk_f32_fp8((int)h.x, false);
      auto p1 = __builtin_amdgcn_cvt_pk_f32_fp8((int)h.x, true);
      auto p2 = __builtin_amdgcn_cvt_pk_f32_fp8((int)h.y, false);
      auto p3 = __builtin_amdgcn_cvt_pk_f32_fp8((int)h.y, true);
      auto p4 = __builtin_amdgcn_cvt_pk_f32_fp8((int)h.z, false);
      auto p5 = __builtin_amdgcn_cvt_pk_f32_fp8((int)h.z, true);
      auto p6 = __builtin_amdgcn_cvt_pk_f32_fp8((int)h.w, false);
      auto p7 = __builtin_amdgcn_cvt_pk_f32_fp8((int)h.w, true);
      acc[0] += w * p0[0];  acc[1] += w * p0[1];
      acc[2] += w * p1[0];  acc[3] += w * p1[1];
      acc[4] += w * p2[0];  acc[5] += w * p2[1];
      acc[6] += w * p3[0];  acc[7] += w * p3[1];
      acc[8] += w * p4[0];  acc[9] += w * p4[1];
      acc[10] += w * p5[0]; acc[11] += w * p5[1];
      acc[12] += w * p6[0]; acc[13] += w * p6[1];
      acc[14] += w * p7[0]; acc[15] += w * p7[1];
    }

    sw += __shfl_xor(sw, 8, 64);
    sw += __shfl_xor(sw, 16, 64);
    sw += __shfl_xor(sw, 32, 64);
    const float inv = 1.f / fmaxf(sw, 1e-16f);
#pragma unroll
    for (int j = 0; j < 16; j++) res[j] += acc[j] * inv;
  }

#pragma unroll
  for (int j = 0; j < 16; j++) {
    res[j] += __shfl_xor(res[j], 8, 64);
    res[j] += __shfl_xor(res[j], 16, 64);
    res[j] += __shfl_xor(res[j], 32, 64);
  }

  const int d = sub * 16 + slot * 2;
  float2 bb0 = *(const float2*)&b0[d];
  float2 bb1 = *(const float2*)&b1[d];
  float v0 = res[slot * 2] + bb0.x + bb1.x;
  float v1 = res[slot * 2 + 1] + bb0.y + bb1.y;
  ushort2 o; o.x = f2bf(v0); o.y = f2bf(v1);
  *(ushort2*)&outb[(size_t)node * DIM + d] = o;
}

// ---------------------------------------------------------------------------
// The whole pipeline as one cooperative kernel. grid.sync() between phases
// replaces ~13 dispatch boundaries (~10us each measured r7->r8 arithmetic).
__global__ __launch_bounds__(256, 4) void mega_k(MegaArgs a) {
  cg::grid_group grid = cg::this_grid();
  const int nb = gridDim.x;
  const int bid = blockIdx.x;
  const int tid = threadIdx.x;
  const int gtid = bid * 256 + tid;
  const int nthr = nb * 256;

  // P0: zero cnt[0..3] + csum (contiguous in ws)
  {
    const int total = 4 * (NE_N + 4) + DIM;
    int* z = a.cnt[0];
    for (int i = gtid; i < total; i += nthr) z[i] = 0;
  }
  grid.sync();

  // P1: setup (conv_w | vec | hist+rank)
  for (int vb = bid; vb < SU_CW + SU_V + SU_H; vb += nb) setup_body(vb, a);
  grid.sync();

  // P2-P4: hierarchical CSR scan
  for (int vb = bid; vb < 4 * 49; vb += nb) {
    scanA_body(vb / 49, vb % 49, a);
    __syncthreads();  // shared-scratch WAR between virtual blocks
  }
  grid.sync();
  if (bid == 0) scanB_body(a);
  grid.sync();
  for (int vb = bid; vb < 4 * 49; vb += nb) {
    scanC_body(vb / 49, vb % 49, a);
    __syncthreads();
  }
  grid.sync();

  // P5: atomic-free fill + layer-0 gemm (fp32 input)
  for (int vb = bid; vb < GEMM_BLK + FILL_BLK; vb += nb) {
    if (vb < GEMM_BLK)
      gemm_body<true>(vb, a.x_elem, a.x_proc, a, 0);
    else
      fill_one(vb - GEMM_BLK, a);
  }
  grid.sync();

  // layers
  for (int l = 0; l < 3; l++) {
    if (l > 0) {
      const ushort* xe = (l == 1) ? a.xe1 : a.xe0;
      const ushort* xp = (l == 1) ? a.xp1 : a.xp0;
      for (int vb = bid; vb < GEMM_BLK; vb += nb)
        gemm_body<false>(vb, xe, xp, a, l);
      grid.sync();
    }
    ushort* oxe = (l & 1) ? a.xe0 : a.xe1;  // l0->xe1, l1->xe0, l2->xe1
    ushort* oxp = (l & 1) ? a.xp0 : a.xp1;
    const int wav0 = gtid >> 6;
    const int wstride = nthr >> 6;
    for (int w = wav0; w < NE_N + NP_N; w += wstride)
      gather_one(w, a, l, oxe, oxp);
    grid.sync();
  }

  // colsum (final features in xe1/xp1); stride is multiple of 128 so each
  // thread stays on one column
  {
    float s = 0.f;
    for (int idx = gtid; idx < NE_N * DIM; idx += nthr) s += bf2f(a.xe1[idx]);
    for (int idx = gtid; idx < NP_N * DIM; idx += nthr) s += bf2f(a.xp1[idx]);
    __shared__ float ls[256];
    ls[tid] = s;
    __syncthreads();
    if (tid < 128)
      unsafeAtomicAdd(&a.csum[tid], ls[tid] + ls[tid + 128]);
  }
  grid.sync();

  if (bid == 0 && tid < 2) {
    float s = 0.f;
#pragma unroll 8
    for (int k = 0; k < DIM; k++) s += a.csum[k] * a.lin_W[k * 2 + tid];
    a.out[tid] = s / (float)(NE_N + NP_N) + a.lin_b[tid];
  }
}

// ---------------------------------------------------------------------------
extern "C" void kernel_launch(void* const* d_in, const int* in_sizes, int n_in,
                              void* d_out, int out_size, void* d_ws,
                              size_t ws_size, hipStream_t stream) {
  MegaArgs a;
  a.x_elem  = (const float*)d_in[0];
  a.x_proc  = (const float*)d_in[1];
  a.W_src   = (const float*)d_in[2];
  a.W_dst   = (const float*)d_in[3];
  a.att_src = (const float*)d_in[4];
  a.att_dst = (const float*)d_in[5];
  a.bias    = (const float*)d_in[6];
  a.lin_W   = (const float*)d_in[7];
  a.lin_b   = (const float*)d_in[8];
  for (int t = 0; t < 4; t++) {
    a.esr[t] = (const int*)d_in[9 + 2 * t];
    a.edl[t] = (const int*)d_in[10 + 2 * t];
  }

  // ---- workspace carve-up (16B-aligned chunks) ----
  char* p = (char*)d_ws;
  a.xe0 = (ushort*)p; p += (size_t)NE_N * DIM * 2;
  a.xe1 = (ushort*)p; p += (size_t)NE_N * DIM * 2;
  a.xp0 = (ushort*)p; p += (size_t)NP_N * DIM * 2;
  a.xp1 = (ushort*)p; p += (size_t)NP_N * DIM * 2;
  a.hsE0 = (unsigned char*)p; p += (size_t)NE_N * DIM;
  a.hsE1 = (unsigned char*)p; p += (size_t)NE_N * DIM;
  a.hsP3 = (unsigned char*)p; p += (size_t)NP_N * DIM;
  a.hsP2 = (unsigned char*)p; p += (size_t)NP_N * DIM;
  a.WbT = (ushort*)p; p += (size_t)12 * DIM * DIM * 2;
  a.esE0 = (float*)p; p += (size_t)NE_N * 4;
  a.esE1 = (float*)p; p += (size_t)NE_N * 4;
  a.esP3 = (float*)p; p += (size_t)NP_N * 4;
  a.esP2 = (float*)p; p += (size_t)NP_N * 4;
  a.edEA = (float*)p; p += (size_t)NE_N * 4;
  a.edEB = (float*)p; p += (size_t)NE_N * 4;
  a.edPA = (float*)p; p += (size_t)NP_N * 4;
  a.edPB = (float*)p; p += (size_t)NP_N * 4;
  a.vec = (float*)p; p += 12 * DIM * 4;
  a.parti = (int*)p; p += 4 * 64 * 4;
  a.part_excl = (int*)p; p += 4 * 64 * 4;
  // cnt[0..3] + csum contiguous (P0 zeroes them as one range)
  for (int t = 0; t < 4; t++) { a.cnt[t] = (int*)p; p += (NE_N + 4) * 4; }
  a.csum = (float*)p; p += DIM * 4;
  for (int t = 0; t < 4; t++) { a.rp[t] = (int*)p; p += (NE_N + 4) * 4; }
  for (int t = 0; t < 4; t++) { a.ss[t] = (ushort*)p; p += (size_t)E_N * 2; }
  for (int t = 0; t < 4; t++) { a.rk[t] = (ushort*)p; p += (size_t)E_N * 2; }
  a.out = (float*)d_out;

  int maxB = 0;
  hipOccupancyMaxActiveBlocksPerMultiprocessor(&maxB, mega_k, 256, 0);
  if (maxB < 1) maxB = 1;
  if (maxB > 8) maxB = 8;
  int grid = maxB * 256;  // 256 CUs, co-resident by construction

  void* params[] = {&a};
  hipLaunchCooperativeKernel(mega_k, dim3(grid), dim3(256), params, 0u,
                             stream);
}

// Round 12
// 496.636 us; speedup vs baseline: 3.0578x; 3.0578x over previous
//
#include <hip/hip_runtime.h>

#define NE_N 50000
#define NP_N 25000
#define E_N 200000
#define DIM 128
#define LOG2E 1.4426950408889634f

typedef __attribute__((ext_vector_type(8))) short short8;
typedef __attribute__((ext_vector_type(4))) float f32x4;

static __device__ __forceinline__ ushort f2bf(float f) {
  unsigned x = __float_as_uint(f);
  return (ushort)((x + 0x7fffu + ((x >> 16) & 1u)) >> 16);  // RNE
}
static __device__ __forceinline__ float bf2f(ushort u) {
  return __uint_as_float(((unsigned)u) << 16);
}

// ---------------------------------------------------------------------------
// Fused setup: conv_w (12 blk) | vec (6 blk) | hist+rank (3128 blk).
// hist's atomicAdd return value IS the edge's rank within its dst segment —
// stored to make the later CSR fill atomic-free.
#define SU_CW 12
#define SU_V 6
#define SU_H 3128
__global__ __launch_bounds__(256) void setup_fused(
    const float* __restrict__ W_src, const float* __restrict__ W_dst,
    const float* __restrict__ att_dst, ushort* __restrict__ WbT,
    float* __restrict__ vec, const int* __restrict__ d0,
    const int* __restrict__ d1, const int* __restrict__ d2,
    const int* __restrict__ d3, int* __restrict__ c0, int* __restrict__ c1,
    int* __restrict__ c2, int* __restrict__ c3, ushort* __restrict__ rk0,
    ushort* __restrict__ rk1, ushort* __restrict__ rk2,
    ushort* __restrict__ rk3) {
  int blk = blockIdx.x;
  int tid = threadIdx.x;
  if (blk < SU_CW) {
    // W transpose->bf16
    const float* src = W_src + (size_t)blk * DIM * DIM;
    ushort* dst = WbT + (size_t)blk * DIM * DIM;
    for (int i = tid; i < DIM * DIM; i += 256) {
      int k = i >> 7, n = i & 127;
      dst[n * DIM + k] = f2bf(src[i]);
    }
  } else if (blk < SU_CW + SU_V) {
    // vec[lt] = W_dst[lt] @ att_dst[lt]
    int b = blk - SU_CW;
    int lt = b * 2 + (tid >> 7);
    int i = tid & 127;
    const float* Wd = W_dst + (size_t)lt * DIM * DIM;
    const float* ad = att_dst + lt * DIM;
    float s = 0.f;
#pragma unroll 8
    for (int j = 0; j < DIM; j++) s += Wd[i * DIM + j] * ad[j];
    vec[lt * DIM + i] = s;
  } else {
    // histogram of dst per type + per-edge rank
    int b = blk - SU_CW - SU_V;
    int ty = b / 782;
    int e = (b % 782) * 256 + tid;
    if (e >= E_N) return;
    const int* dst = ty == 0 ? d0 : ty == 1 ? d1 : ty == 2 ? d2 : d3;
    int* cnt = ty == 0 ? c0 : ty == 1 ? c1 : ty == 2 ? c2 : c3;
    ushort* rk = ty == 0 ? rk0 : ty == 1 ? rk1 : ty == 2 ? rk2 : rk3;
    rk[e] = (ushort)atomicAdd(&cnt[dst[e]], 1);
  }
}

// ---------------------------------------------------------------------------
// 3-phase hierarchical CSR scan (measured-good; r9's 1-dispatch scan was
// 92us and r11's coop mega-kernel was 1519us — multi-dispatch stays).
__global__ __launch_bounds__(256) void scanA_k(
    const int* __restrict__ c0, const int* __restrict__ c1,
    const int* __restrict__ c2, const int* __restrict__ c3,
    int* __restrict__ part) {
  int ty = blockIdx.y;
  const int* cnt = ty == 0 ? c0 : ty == 1 ? c1 : ty == 2 ? c2 : c3;
  int n = (ty == 0 || ty == 3) ? NE_N : NP_N;
  int nblk = (n + 1023) >> 10;
  if ((int)blockIdx.x >= nblk) return;
  int base = blockIdx.x * 1024 + threadIdx.x * 4;
  int s = 0;
#pragma unroll
  for (int j = 0; j < 4; j++) s += (base + j < n) ? cnt[base + j] : 0;
  int lane = threadIdx.x & 63, wid = threadIdx.x >> 6;
#pragma unroll
  for (int off = 32; off > 0; off >>= 1) s += __shfl_xor(s, off, 64);
  __shared__ int ws4[4];
  if (lane == 0) ws4[wid] = s;
  __syncthreads();
  if (threadIdx.x == 0)
    part[ty * 64 + blockIdx.x] = ws4[0] + ws4[1] + ws4[2] + ws4[3];
}

__global__ __launch_bounds__(256) void scanB_k(
    const int* __restrict__ part, int* __restrict__ part_excl,
    int* __restrict__ r0, int* __restrict__ r1, int* __restrict__ r2,
    int* __restrict__ r3) {
  int ty = threadIdx.x >> 6, lane = threadIdx.x & 63;
  int n = (ty == 0 || ty == 3) ? NE_N : NP_N;
  int nblk = (n + 1023) >> 10;
  int v = (lane < nblk) ? part[ty * 64 + lane] : 0;
  int sc = v;
#pragma unroll
  for (int off = 1; off < 64; off <<= 1) {
    int t = __shfl_up(sc, off, 64);
    if (lane >= off) sc += t;
  }
  if (lane < nblk) part_excl[ty * 64 + lane] = sc - v;
  if (lane == nblk - 1) {
    int* rp = ty == 0 ? r0 : ty == 1 ? r1 : ty == 2 ? r2 : r3;
    rp[n] = sc;  // total
  }
}

__global__ __launch_bounds__(256) void scanC_k(
    const int* __restrict__ c0, const int* __restrict__ c1,
    const int* __restrict__ c2, const int* __restrict__ c3,
    int* __restrict__ r0, int* __restrict__ r1, int* __restrict__ r2,
    int* __restrict__ r3, const int* __restrict__ part_excl) {
  int ty = blockIdx.y;
  const int* cnt = ty == 0 ? c0 : ty == 1 ? c1 : ty == 2 ? c2 : c3;
  int* rp = ty == 0 ? r0 : ty == 1 ? r1 : ty == 2 ? r2 : r3;
  int n = (ty == 0 || ty == 3) ? NE_N : NP_N;
  int nblk = (n + 1023) >> 10;
  if ((int)blockIdx.x >= nblk) return;
  int base = blockIdx.x * 1024 + threadIdx.x * 4;
  int v[4];
#pragma unroll
  for (int j = 0; j < 4; j++) v[j] = (base + j < n) ? cnt[base + j] : 0;
  int s = v[0] + v[1] + v[2] + v[3];
  int lane = threadIdx.x & 63, wid = threadIdx.x >> 6;
  int sc = s;
#pragma unroll
  for (int off = 1; off < 64; off <<= 1) {
    int t = __shfl_up(sc, off, 64);
    if (lane >= off) sc += t;
  }
  __shared__ int ws4[4];
  if (lane == 63) ws4[wid] = sc;
  __syncthreads();
  int wbase = 0;
  for (int w = 0; w < wid; w++) wbase += ws4[w];
  int p = part_excl[ty * 64 + blockIdx.x] + wbase + sc - s;
#pragma unroll
  for (int j = 0; j < 4; j++) {
    if (base + j < n) rp[base + j] = p;
    p += v[j];
  }
}

// ---------------------------------------------------------------------------
// GEMM body: operand-swapped MFMA; es (scaled LOG2E) + ed for both dst
// halves. FP32 template: layer 0 reads raw fp32 features (no conv pass).
#define EBLK ((NE_N + 63) / 64)
#define PBLK ((NP_N + 63) / 64)
#define GEMM_BLK (EBLK + PBLK)
template <bool FP32>
static __device__ __forceinline__ void gemm_body(
    int blk, const void* __restrict__ xev, const void* __restrict__ xpv,
    const ushort* __restrict__ WbT, const float* __restrict__ att,
    const float* __restrict__ vec, int l, unsigned char* __restrict__ hsE0,
    unsigned char* __restrict__ hsE1, unsigned char* __restrict__ hsP3,
    unsigned char* __restrict__ hsP2, float* __restrict__ esE0,
    float* __restrict__ esE1, float* __restrict__ esP3,
    float* __restrict__ esP2, float* __restrict__ edEA,
    float* __restrict__ edEB, float* __restrict__ edPA,
    float* __restrict__ edPB) {
  const void* xb;
  const ushort *W0T, *W1T;
  const float *a0, *a1, *dv0, *dv1;
  unsigned char *hs0, *hs1;
  float *es0, *es1, *edA, *edB;
  int N;
  if (blk < EBLK) {
    xb = xev; N = NE_N;
    W0T = WbT + (size_t)(l * 4 + 0) * DIM * DIM;
    W1T = WbT + (size_t)(l * 4 + 1) * DIM * DIM;
    a0 = att + (l * 4 + 0) * DIM; a1 = att + (l * 4 + 1) * DIM;
    dv0 = vec + (l * 4 + 0) * DIM; dv1 = vec + (l * 4 + 3) * DIM;
    hs0 = hsE0; hs1 = hsE1; es0 = esE0; es1 = esE1;
    edA = edEA; edB = edEB;
  } else {
    blk -= EBLK; xb = xpv; N = NP_N;
    W0T = WbT + (size_t)(l * 4 + 3) * DIM * DIM;
    W1T = WbT + (size_t)(l * 4 + 2) * DIM * DIM;
    a0 = att + (l * 4 + 3) * DIM; a1 = att + (l * 4 + 2) * DIM;
    dv0 = vec + (l * 4 + 1) * DIM; dv1 = vec + (l * 4 + 2) * DIM;
    hs0 = hsP3; hs1 = hsP2; es0 = esP3; es1 = esP2;
    edA = edPA; edB = edPB;
  }

  const int wave = threadIdx.x >> 6;
  const int lane = threadIdx.x & 63;
  const int m = lane & 15, quad = lane >> 4;
  const int row0 = blk * 64 + wave * 16;
  if (row0 >= N) return;
  int rowA = row0 + m;
  if (rowA >= N) rowA = N - 1;  // clamp loads; stores guarded

  f32x4 acc0[8], acc1[8];
#pragma unroll
  for (int f = 0; f < 8; f++) {
    acc0[f] = (f32x4){0.f, 0.f, 0.f, 0.f};
    acc1[f] = (f32x4){0.f, 0.f, 0.f, 0.f};
  }

  float edp0 = 0.f, edp1 = 0.f;
  const float* xf32 = (const float*)xb + (size_t)rowA * DIM + quad * 8;
  const ushort* xb16 = (const ushort*)xb + (size_t)rowA * DIM + quad * 8;
#pragma unroll
  for (int k0 = 0; k0 < 4; k0++) {
    short8 xv;
    float xf[8];
    if (FP32) {
      float4 f0 = *(const float4*)(xf32 + k0 * 32);
      float4 f1 = *(const float4*)(xf32 + k0 * 32 + 4);
      xf[0] = f0.x; xf[1] = f0.y; xf[2] = f0.z; xf[3] = f0.w;
      xf[4] = f1.x; xf[5] = f1.y; xf[6] = f1.z; xf[7] = f1.w;
#pragma unroll
      for (int j = 0; j < 8; j++) xv[j] = (short)f2bf(xf[j]);
    } else {
      xv = *(const short8*)(xb16 + k0 * 32);
#pragma unroll
      for (int j = 0; j < 8; j++) xf[j] = bf2f((ushort)xv[j]);
    }
    // ed partials
    {
      int off = k0 * 32 + quad * 8;
      float4 vA0 = *(const float4*)&dv0[off];
      float4 vA1 = *(const float4*)&dv0[off + 4];
      float4 vB0 = *(const float4*)&dv1[off];
      float4 vB1 = *(const float4*)&dv1[off + 4];
      edp0 += xf[0] * vA0.x + xf[1] * vA0.y + xf[2] * vA0.z + xf[3] * vA0.w +
              xf[4] * vA1.x + xf[5] * vA1.y + xf[6] * vA1.z + xf[7] * vA1.w;
      edp1 += xf[0] * vB0.x + xf[1] * vB0.y + xf[2] * vB0.z + xf[3] * vB0.w +
              xf[4] * vB1.x + xf[5] * vB1.y + xf[6] * vB1.z + xf[7] * vB1.w;
    }
#pragma unroll
    for (int f = 0; f < 8; f++) {
      size_t boff = (size_t)(f * 16 + m) * DIM + k0 * 32 + quad * 8;
      short8 w0 = *(const short8*)(W0T + boff);
      acc0[f] = __builtin_amdgcn_mfma_f32_16x16x32_bf16(w0, xv, acc0[f], 0, 0, 0);
      short8 w1 = *(const short8*)(W1T + boff);
      acc1[f] = __builtin_amdgcn_mfma_f32_16x16x32_bf16(w1, xv, acc1[f], 0, 0, 0);
    }
  }

  const int row = row0 + m;
  // ed: reduce over quad, store scaled by LOG2E
  edp0 += __shfl_xor(edp0, 16, 64);
  edp0 += __shfl_xor(edp0, 32, 64);
  edp1 += __shfl_xor(edp1, 16, 64);
  edp1 += __shfl_xor(edp1, 32, 64);
  if (quad == 0 && row < N) {
    edA[row] = edp0 * LOG2E;
    edB[row] = edp1 * LOG2E;
  }

#pragma unroll
  for (int set = 0; set < 2; set++) {
    f32x4* acc = set ? acc1 : acc0;
    const float* as = set ? a1 : a0;
    float* es = set ? es1 : es0;
    unsigned char* hs = set ? hs1 : hs0;

    float esum = 0.f;
#pragma unroll
    for (int f = 0; f < 8; f++) {
      float4 av = *(const float4*)&as[f * 16 + quad * 4];
      esum += acc[f][0] * av.x + acc[f][1] * av.y + acc[f][2] * av.z +
              acc[f][3] * av.w;
    }
    esum += __shfl_xor(esum, 16, 64);
    esum += __shfl_xor(esum, 32, 64);
    if (quad == 0 && row < N) es[row] = esum * LOG2E;

    if (row < N) {
#pragma unroll
      for (int f = 0; f < 8; f++) {
        int w = __builtin_amdgcn_cvt_pk_fp8_f32(acc[f][0], acc[f][1], 0, false);
        w = __builtin_amdgcn_cvt_pk_fp8_f32(acc[f][2], acc[f][3], w, true);
        *(unsigned*)&hs[(size_t)row * DIM + f * 16 + quad * 4] = (unsigned)w;
      }
    }
  }
}

// standalone gemm (layers 1,2 — bf16 input)
__global__ __launch_bounds__(256) void gemm_k(
    const ushort* __restrict__ xe, const ushort* __restrict__ xp,
    const ushort* __restrict__ WbT, const float* __restrict__ att,
    const float* __restrict__ vec, int l, unsigned char* __restrict__ hsE0,
    unsigned char* __restrict__ hsE1, unsigned char* __restrict__ hsP3,
    unsigned char* __restrict__ hsP2, float* __restrict__ esE0,
    float* __restrict__ esE1, float* __restrict__ esP3,
    float* __restrict__ esP2, float* __restrict__ edEA,
    float* __restrict__ edEB, float* __restrict__ edPA,
    float* __restrict__ edPB) {
  gemm_body<false>(blockIdx.x, xe, xp, WbT, att, vec, l, hsE0, hsE1, hsP3,
                   hsP2, esE0, esE1, esP3, esP2, edEA, edEB, edPA, edPB);
}

// fused atomic-free CSR-fill + layer-0 gemm (fp32 input)
__global__ __launch_bounds__(256) void fill_gemm0_k(
    const float* __restrict__ xe, const float* __restrict__ xp,
    const ushort* __restrict__ WbT, const float* __restrict__ att,
    const float* __restrict__ vec, unsigned char* __restrict__ hsE0,
    unsigned char* __restrict__ hsE1, unsigned char* __restrict__ hsP3,
    unsigned char* __restrict__ hsP2, float* __restrict__ esE0,
    float* __restrict__ esE1, float* __restrict__ esP3,
    float* __restrict__ esP2, float* __restrict__ edEA,
    float* __restrict__ edEB, float* __restrict__ edPA,
    float* __restrict__ edPB, const int* __restrict__ s0,
    const int* __restrict__ s1, const int* __restrict__ s2,
    const int* __restrict__ s3, const int* __restrict__ d0,
    const int* __restrict__ d1, const int* __restrict__ d2,
    const int* __restrict__ d3, const ushort* __restrict__ rk0,
    const ushort* __restrict__ rk1, const ushort* __restrict__ rk2,
    const ushort* __restrict__ rk3, const int* __restrict__ r0,
    const int* __restrict__ r1, const int* __restrict__ r2,
    const int* __restrict__ r3, ushort* __restrict__ o0,
    ushort* __restrict__ o1, ushort* __restrict__ o2,
    ushort* __restrict__ o3) {
  int blk = blockIdx.x;
  if (blk < GEMM_BLK) {
    gemm_body<true>(blk, xe, xp, WbT, att, vec, 0, hsE0, hsE1, hsP3, hsP2,
                    esE0, esE1, esP3, esP2, edEA, edEB, edPA, edPB);
  } else {
    int b = blk - GEMM_BLK;
    int ty = b / 782;
    int e = (b % 782) * 256 + threadIdx.x;
    if (e >= E_N) return;
    const int* src = ty == 0 ? s0 : ty == 1 ? s1 : ty == 2 ? s2 : s3;
    const int* dst = ty == 0 ? d0 : ty == 1 ? d1 : ty == 2 ? d2 : d3;
    const ushort* rk = ty == 0 ? rk0 : ty == 1 ? rk1 : ty == 2 ? rk2 : rk3;
    const int* rp = ty == 0 ? r0 : ty == 1 ? r1 : ty == 2 ? r2 : r3;
    ushort* out = ty == 0 ? o0 : ty == 1 ? o1 : ty == 2 ? o2 : o3;
    // atomic-free: position = segment base + precomputed rank
    out[rp[dst[e]] + rk[e]] = (ushort)src[e];
  }
}

// ---------------------------------------------------------------------------
// Combined dual-type gather. NEW: the two type-halves run CONCURRENTLY —
// slots 0-3 walk half A's edges, slots 4-7 walk half B's (stride 4). Both
// dependent load chains (ss -> es/hs) are in flight at once, halving the
// serial memory phases per node (avg degree is only ~4 per half for e-dst).
// 8 sublanes x 16B fp8 row loads; es/ed pre-scaled by LOG2E -> exp2.
__global__ __launch_bounds__(256) void gat_gather_all(
    const int* __restrict__ rp0, const ushort* __restrict__ ss0,
    const int* __restrict__ rp1, const ushort* __restrict__ ss1,
    const int* __restrict__ rp2, const ushort* __restrict__ ss2,
    const int* __restrict__ rp3, const ushort* __restrict__ ss3,
    const float* __restrict__ esE0, const unsigned char* __restrict__ hsE0,
    const float* __restrict__ esE1, const unsigned char* __restrict__ hsE1,
    const float* __restrict__ esP3, const unsigned char* __restrict__ hsP3,
    const float* __restrict__ esP2, const unsigned char* __restrict__ hsP2,
    const float* __restrict__ edEA, const float* __restrict__ edEB,
    const float* __restrict__ edPA, const float* __restrict__ edPB,
    const float* __restrict__ bias, int l, ushort* __restrict__ outxe,
    ushort* __restrict__ outxp) {
  const int wid = (blockIdx.x * 256 + threadIdx.x) >> 6;
  const int lane = threadIdx.x & 63;
  const int slot = lane >> 3, sub = lane & 7;
  const int half = slot >> 2;   // 0: type-half A, 1: type-half B
  const int hslot = slot & 3;   // slot within the half

  int node;
  const int *rpA, *rpB;
  const ushort *ssA, *ssB;
  const float *esA, *esB;
  const unsigned char *hsA, *hsB;
  const float *edA, *edB;
  const float *b0, *b1;
  ushort* outb;
  if (wid < NE_N) {  // e-dst: ee (A) + pe (B)
    node = wid;
    rpA = rp0; ssA = ss0; esA = esE0; hsA = hsE0;
    rpB = rp3; ssB = ss3; esB = esP3; hsB = hsP3;
    edA = edEA; edB = edEB;
    b0 = bias + (l * 4 + 0) * DIM; b1 = bias + (l * 4 + 3) * DIM;
    outb = outxe;
  } else if (wid < NE_N + NP_N) {  // p-dst: ep (A) + pp (B)
    node = wid - NE_N;
    rpA = rp1; ssA = ss1; esA = esE1; hsA = hsE1;
    rpB = rp2; ssB = ss2; esB = esP2; hsB = hsP2;
    edA = edPA; edB = edPB;
    b0 = bias + (l * 4 + 1) * DIM; b1 = bias + (l * 4 + 2) * DIM;
    outb = outxp;
  } else {
    return;
  }

  // per-lane half-specific views
  const int* rp = half ? rpB : rpA;
  const ushort* ss = half ? ssB : ssA;
  const float* es = half ? esB : esA;
  const unsigned char* hs = half ? hsB : hsA;
  const float edv = half ? edB[node] : edA[node];
  const int beg = rp[node], end = rp[node + 1];

  float acc[16];
#pragma unroll
  for (int j = 0; j < 16; j++) acc[j] = 0.f;
  float sw = 0.f;

  // single pass over this half's edges, 4 slots in flight per half
  for (int e = beg + hslot; e < end; e += 4) {
    int s = ss[e];
    float w = exp2f(fmaxf(es[s] + edv, 0.f));
    sw += w;
    uint4 h = *(const uint4*)&hs[(size_t)s * DIM + sub * 16];
    auto p0 = __builtin_amdgcn_cvt_pk_f32_fp8((int)h.x, false);
    auto p1 = __builtin_amdgcn_cvt_pk_f32_fp8((int)h.x, true);
    auto p2 = __builtin_amdgcn_cvt_pk_f32_fp8((int)h.y, false);
    auto p3 = __builtin_amdgcn_cvt_pk_f32_fp8((int)h.y, true);
    auto p4 = __builtin_amdgcn_cvt_pk_f32_fp8((int)h.z, false);
    auto p5 = __builtin_amdgcn_cvt_pk_f32_fp8((int)h.z, true);
    auto p6 = __builtin_amdgcn_cvt_pk_f32_fp8((int)h.w, false);
    auto p7 = __builtin_amdgcn_cvt_pk_f32_fp8((int)h.w, true);
    acc[0] += w * p0[0];  acc[1] += w * p0[1];
    acc[2] += w * p1[0];  acc[3] += w * p1[1];
    acc[4] += w * p2[0];  acc[5] += w * p2[1];
    acc[6] += w * p3[0];  acc[7] += w * p3[1];
    acc[8] += w * p4[0];  acc[9] += w * p4[1];
    acc[10] += w * p5[0]; acc[11] += w * p5[1];
    acc[12] += w * p6[0]; acc[13] += w * p6[1];
    acc[14] += w * p7[0]; acc[15] += w * p7[1];
  }

  // sw: reduce over the 4 slots of THIS half (lane bits 3,4)
  sw += __shfl_xor(sw, 8, 64);
  sw += __shfl_xor(sw, 16, 64);
  const float inv = 1.f / fmaxf(sw, 1e-16f);

  float res[16];
#pragma unroll
  for (int j = 0; j < 16; j++) res[j] = acc[j] * inv;

  // combine: 4 slot-partials within half (xor 8,16) + across halves (xor 32)
#pragma unroll
  for (int j = 0; j < 16; j++) {
    res[j] += __shfl_xor(res[j], 8, 64);
    res[j] += __shfl_xor(res[j], 16, 64);
    res[j] += __shfl_xor(res[j], 32, 64);
  }

  // lane stores dims d, d+1 where d = sub*16 + slot*2 (coalesced 256B row)
  const int d = sub * 16 + slot * 2;
  float2 bb0 = *(const float2*)&b0[d];
  float2 bb1 = *(const float2*)&b1[d];
  float v0 = res[slot * 2] + bb0.x + bb1.x;
  float v1 = res[slot * 2 + 1] + bb0.y + bb1.y;
  ushort2 o; o.x = f2bf(v0); o.y = f2bf(v1);
  *(ushort2*)&outb[(size_t)node * DIM + d] = o;
}

// ---------------------------------------------------------------------------
__global__ __launch_bounds__(256) void colsum_k(
    const ushort* __restrict__ xe, const ushort* __restrict__ xp,
    float* __restrict__ colsum) {
  int tid = blockIdx.x * 256 + threadIdx.x;
  const int stride = 256 * 256;  // multiple of 128 -> fixed column per thread
  float s = 0.f;
  for (int idx = tid; idx < NE_N * DIM; idx += stride) s += bf2f(xe[idx]);
  for (int idx = tid; idx < NP_N * DIM; idx += stride) s += bf2f(xp[idx]);
  __shared__ float ls[256];
  ls[threadIdx.x] = s;
  __syncthreads();
  if (threadIdx.x < 128)
    unsafeAtomicAdd(&colsum[threadIdx.x], ls[threadIdx.x] + ls[threadIdx.x + 128]);
}

// ---------------------------------------------------------------------------
__global__ void final_proj(const float* __restrict__ colsum,
                           const float* __restrict__ lin_W,
                           const float* __restrict__ lin_b,
                           float* __restrict__ out) {
  int j = threadIdx.x;
  if (j >= 2) return;
  float s = 0.f;
#pragma unroll 8
  for (int k = 0; k < DIM; k++) s += colsum[k] * lin_W[k * 2 + j];
  out[j] = s / (float)(NE_N + NP_N) + lin_b[j];
}

// ---------------------------------------------------------------------------
extern "C" void kernel_launch(void* const* d_in, const int* in_sizes, int n_in,
                              void* d_out, int out_size, void* d_ws,
                              size_t ws_size, hipStream_t stream) {
  const float* x_elem  = (const float*)d_in[0];
  const float* x_proc  = (const float*)d_in[1];
  const float* W_src   = (const float*)d_in[2];
  const float* W_dst   = (const float*)d_in[3];
  const float* att_src = (const float*)d_in[4];
  const float* att_dst = (const float*)d_in[5];
  const float* bias    = (const float*)d_in[6];
  const float* lin_W   = (const float*)d_in[7];
  const float* lin_b   = (const float*)d_in[8];
  const int* esrc[4] = {(const int*)d_in[9],  (const int*)d_in[11],
                        (const int*)d_in[13], (const int*)d_in[15]};
  const int* edst[4] = {(const int*)d_in[10], (const int*)d_in[12],
                        (const int*)d_in[14], (const int*)d_in[16]};

  // ---- workspace carve-up (16B-aligned chunks) ----
  char* p = (char*)d_ws;
  ushort* xe_bf[2]; ushort* xp_bf[2];
  xe_bf[0] = (ushort*)p; p += (size_t)NE_N * DIM * 2;
  xe_bf[1] = (ushort*)p; p += (size_t)NE_N * DIM * 2;
  xp_bf[0] = (ushort*)p; p += (size_t)NP_N * DIM * 2;
  xp_bf[1] = (ushort*)p; p += (size_t)NP_N * DIM * 2;
  unsigned char* hsE0 = (unsigned char*)p; p += (size_t)NE_N * DIM;  // W[l,0]
  unsigned char* hsE1 = (unsigned char*)p; p += (size_t)NE_N * DIM;  // W[l,1]
  unsigned char* hsP3 = (unsigned char*)p; p += (size_t)NP_N * DIM;  // W[l,3]
  unsigned char* hsP2 = (unsigned char*)p; p += (size_t)NP_N * DIM;  // W[l,2]
  ushort* WbT = (ushort*)p; p += (size_t)12 * DIM * DIM * 2;
  float* esE0 = (float*)p; p += (size_t)NE_N * 4;
  float* esE1 = (float*)p; p += (size_t)NE_N * 4;
  float* esP3 = (float*)p; p += (size_t)NP_N * 4;
  float* esP2 = (float*)p; p += (size_t)NP_N * 4;
  float* edEA = (float*)p; p += (size_t)NE_N * 4;
  float* edEB = (float*)p; p += (size_t)NE_N * 4;
  float* edPA = (float*)p; p += (size_t)NP_N * 4;
  float* edPB = (float*)p; p += (size_t)NP_N * 4;
  float* vec = (float*)p; p += 12 * DIM * 4;
  int* parti = (int*)p; p += 4 * 64 * 4;
  int* part_excl = (int*)p; p += 4 * 64 * 4;
  // cnt[4] + csum contiguous -> single memset
  int* cnt[4];
  for (int t = 0; t < 4; t++) { cnt[t] = (int*)p; p += (NE_N + 4) * 4; }
  float* csum = (float*)p; p += DIM * 4;
  int* rp[4];
  for (int t = 0; t < 4; t++) { rp[t] = (int*)p; p += (NE_N + 4) * 4; }
  ushort* ssrc[4];
  for (int t = 0; t < 4; t++) { ssrc[t] = (ushort*)p; p += (size_t)E_N * 2; }
  ushort* rank[4];
  for (int t = 0; t < 4; t++) { rank[t] = (ushort*)p; p += (size_t)E_N * 2; }

  // ---- zero cnts + csum in one memset ----
  hipMemsetAsync(cnt[0], 0, 4 * (NE_N + 4) * sizeof(int) + DIM * sizeof(float),
                 stream);

  // ---- fused setup: conv_w | vec | hist+rank ----
  setup_fused<<<SU_CW + SU_V + SU_H, 256, 0, stream>>>(
      W_src, W_dst, att_dst, WbT, vec, edst[0], edst[1], edst[2], edst[3],
      cnt[0], cnt[1], cnt[2], cnt[3], rank[0], rank[1], rank[2], rank[3]);

  // ---- 3-phase hierarchical CSR scan ----
  scanA_k<<<dim3(49, 4), 256, 0, stream>>>(cnt[0], cnt[1], cnt[2], cnt[3],
                                           parti);
  scanB_k<<<1, 256, 0, stream>>>(parti, part_excl, rp[0], rp[1], rp[2], rp[3]);
  scanC_k<<<dim3(49, 4), 256, 0, stream>>>(cnt[0], cnt[1], cnt[2], cnt[3],
                                           rp[0], rp[1], rp[2], rp[3],
                                           part_excl);

  // ---- atomic-free fill + layer-0 gemm (fp32 input) fused ----
  fill_gemm0_k<<<GEMM_BLK + 3128, 256, 0, stream>>>(
      x_elem, x_proc, WbT, att_src, vec, hsE0, hsE1, hsP3, hsP2, esE0, esE1,
      esP3, esP2, edEA, edEB, edPA, edPB, esrc[0], esrc[1], esrc[2], esrc[3],
      edst[0], edst[1], edst[2], edst[3], rank[0], rank[1], rank[2], rank[3],
      rp[0], rp[1], rp[2], rp[3], ssrc[0], ssrc[1], ssrc[2], ssrc[3]);

  // ---- layers ----
  int c = 0;
  for (int l = 0; l < 3; l++) {
    if (l > 0) {
      gemm_k<<<GEMM_BLK, 256, 0, stream>>>(
          xe_bf[c], xp_bf[c], WbT, att_src, vec, l, hsE0, hsE1, hsP3, hsP2,
          esE0, esE1, esP3, esP2, edEA, edEB, edPA, edPB);
    }
    gat_gather_all<<<(NE_N + NP_N) / 4, 256, 0, stream>>>(
        rp[0], ssrc[0], rp[1], ssrc[1], rp[2], ssrc[2], rp[3], ssrc[3], esE0,
        hsE0, esE1, hsE1, esP3, hsP3, esP2, hsP2, edEA, edEB, edPA, edPB,
        bias, l, xe_bf[1 - c], xp_bf[1 - c]);
    c = 1 - c;
  }

  colsum_k<<<256, 256, 0, stream>>>(xe_bf[c], xp_bf[c], csum);
  final_proj<<<1, 64, 0, stream>>>(csum, lin_W, lin_b, (float*)d_out);
}